// Round 1
// 243.482 us; speedup vs baseline: 1.8331x; 1.8331x over previous
//
#include <hip/hip_runtime.h>
#include <math.h>

// Problem constants (fixed by the reference).
#define KCODES 512
#define DDIM   64
#define NROWS  262144
#define ND     ((size_t)NROWS * DDIM)
#define MBLK   64            // rows per block
#define MARGIN 1.5e-4f       // rigorous exclusion margin (see R5 analysis)

// ---------------------------------------------------------------------------
// Architecture (R6):
//  * Same verified filter math as R5: bf16 hi/lo MFMA filter
//    g(k) = c_sqr[k] - 2*x.c[k] (6-MFMA sequence: xh*ch0, xh*ch1, xl*ch0,
//    xl*ch1, xh*cl0, xh*cl1), MARGIN = 1.5e-4 > 2*eta + 2*g_err, candidates
//    within rowmin+MARGIN re-evaluated with the bit-exact numpy replica
//    (sequential-FMA dot, pairwise sumsq, fl(fl(xs+cs)-2mm), strict '<').
//  * NEW: scores never touch LDS. Each row is owned by one 16-lane group
//    (C layout: col=lane&15, row=quad*4+reg), so row-min = in-lane fminf
//    tree + 4-step shfl_xor butterfly; candidate collection = rare LDS
//    atomics. The two 64-iteration serial LDS rescans of R5 are gone.
//  * NEW: codebook pre-packed FRAGMENT-ORDERED by prep (FR[p][tt][f][lane]),
//    so B reads are lane-linear ds_read_b128 (conflict-free) and staging is
//    a linear global_load_lds (16B) issued to overlap with min/collect.
//  * LDS 139 KB -> 36.5 KB, launch_bounds(256,4): 4 blocks/CU (16 waves/CU)
//    instead of 1 block/CU (4 waves). Latency-bound -> overlapped.
// ---------------------------------------------------------------------------

typedef __attribute__((ext_vector_type(8))) short s16x8;
typedef __attribute__((ext_vector_type(4))) float f32x4;
union U4S8 { uint4 u; s16x8 s; };

__device__ __forceinline__ unsigned short bf16_rne(float f) {
    unsigned u = __float_as_uint(f);
    return (unsigned short)((u + 0x7FFFu + ((u >> 16) & 1u)) >> 16);
}
__device__ __forceinline__ float bf16_tof(unsigned short h) {
    return __uint_as_float(((unsigned)h) << 16);
}

// Async global->LDS (gfx950). LDS dest = wave-uniform base + lane*16;
// global source is per-lane. Both sides linear here (fragment-ordered FR).
__device__ __forceinline__ void g2lds16(const void* g, void* l) {
    __builtin_amdgcn_global_load_lds(
        (const __attribute__((address_space(1))) unsigned int*)g,
        (__attribute__((address_space(3))) unsigned int*)l,
        16, 0, 0);
}

// numpy pairwise_sum base case for n=64 (verified bit-exact in R2).
__device__ __forceinline__ float np_sumsq64(const float* v) {
    float r[8];
#pragma unroll
    for (int j = 0; j < 8; ++j) r[j] = __fmul_rn(v[j], v[j]);
#pragma unroll
    for (int i = 8; i < 64; i += 8) {
#pragma unroll
        for (int j = 0; j < 8; ++j)
            r[j] = __fadd_rn(r[j], __fmul_rn(v[i + j], v[i + j]));
    }
    float t01 = __fadd_rn(r[0], r[1]);
    float t23 = __fadd_rn(r[2], r[3]);
    float t45 = __fadd_rn(r[4], r[5]);
    float t67 = __fadd_rn(r[6], r[7]);
    return __fadd_rn(__fadd_rn(t01, t23), __fadd_rn(t45, t67));
}

// Streaming variant (identical op order; low register pressure for the
// rare exact-fallback path executed by m<4 lanes only).
__device__ __forceinline__ float np_xs_stream(const float4* __restrict__ xr) {
    float4 u = xr[0], w = xr[1];
    float r0 = __fmul_rn(u.x, u.x), r1 = __fmul_rn(u.y, u.y);
    float r2 = __fmul_rn(u.z, u.z), r3 = __fmul_rn(u.w, u.w);
    float r4 = __fmul_rn(w.x, w.x), r5 = __fmul_rn(w.y, w.y);
    float r6 = __fmul_rn(w.z, w.z), r7 = __fmul_rn(w.w, w.w);
#pragma unroll
    for (int i = 1; i < 8; ++i) {
        u = xr[2 * i]; w = xr[2 * i + 1];
        r0 = __fadd_rn(r0, __fmul_rn(u.x, u.x));
        r1 = __fadd_rn(r1, __fmul_rn(u.y, u.y));
        r2 = __fadd_rn(r2, __fmul_rn(u.z, u.z));
        r3 = __fadd_rn(r3, __fmul_rn(u.w, u.w));
        r4 = __fadd_rn(r4, __fmul_rn(w.x, w.x));
        r5 = __fadd_rn(r5, __fmul_rn(w.y, w.y));
        r6 = __fadd_rn(r6, __fmul_rn(w.z, w.z));
        r7 = __fadd_rn(r7, __fmul_rn(w.w, w.w));
    }
    float t01 = __fadd_rn(r0, r1), t23 = __fadd_rn(r2, r3);
    float t45 = __fadd_rn(r4, r5), t67 = __fadd_rn(r6, r7);
    return __fadd_rn(__fadd_rn(t01, t23), __fadd_rn(t45, t67));
}

// Sequential-FMA dot in ascending dim order (bit-exact vs reference mm).
__device__ __forceinline__ float dot_seq(const float4* __restrict__ xr,
                                         const float* __restrict__ c) {
    const float4* c4 = (const float4*)c;
    float a = 0.f;
#pragma unroll
    for (int i = 0; i < 16; ++i) {
        float4 xv = xr[i];
        float4 cv = c4[i];
        a = __fmaf_rn(xv.x, cv.x, a);
        a = __fmaf_rn(xv.y, cv.y, a);
        a = __fmaf_rn(xv.z, cv.z, a);
        a = __fmaf_rn(xv.w, cv.w, a);
    }
    return a;
}

// Prep: numpy-exact c_sqr + fragment-ordered bf16 hi/lo codebook.
// FR layout (16B granules): granule index = ((p*8+tt)*4 + f)*64 + lane,
// lane = quad*16 + m, code k = p*128 + tt*16 + m.
//   f=0: hi dims quad*8+j        f=1: hi dims 32+quad*8+j
//   f=2: lo dims quad*8+j        f=3: lo dims 32+quad*8+j
__global__ void vq_prep(const float* __restrict__ cb, float* __restrict__ cs,
                        unsigned short* __restrict__ FR) {
    int k = blockIdx.x * blockDim.x + threadIdx.x;
    if (k < KCODES) {
        float v[DDIM];
        const float4* c4 = (const float4*)(cb + (size_t)k * DDIM);
#pragma unroll
        for (int i = 0; i < DDIM / 4; ++i) {
            float4 t = c4[i];
            v[4 * i + 0] = t.x; v[4 * i + 1] = t.y;
            v[4 * i + 2] = t.z; v[4 * i + 3] = t.w;
        }
        cs[k] = np_sumsq64(v);
        int p = k >> 7, tt = (k >> 4) & 7, mm = k & 15;
        size_t rec = ((size_t)p * 8 + (size_t)tt) * 4;   // frag-granule base
#pragma unroll
        for (int d = 0; d < DDIM; ++d) {
            unsigned short h = bf16_rne(v[d]);
            unsigned short l = bf16_rne(v[d] - bf16_tof(h));
            int quad = (d >> 3) & 3;
            int j = d & 7;
            int fhi = d >> 5;                 // 0 for dims 0..31, 1 for 32..63
            int lane = quad * 16 + mm;
            FR[((rec + fhi) * 64 + lane) * 8 + j] = h;
            FR[((rec + 2 + fhi) * 64 + lane) * 8 + j] = l;
        }
    }
}

__device__ __forceinline__ void pack8(float4 a, float4 b, uint4& hi, uint4& lo) {
    unsigned short h0 = bf16_rne(a.x), h1 = bf16_rne(a.y),
                   h2 = bf16_rne(a.z), h3 = bf16_rne(a.w);
    unsigned short h4 = bf16_rne(b.x), h5 = bf16_rne(b.y),
                   h6 = bf16_rne(b.z), h7 = bf16_rne(b.w);
    unsigned short l0 = bf16_rne(a.x - bf16_tof(h0)), l1 = bf16_rne(a.y - bf16_tof(h1)),
                   l2 = bf16_rne(a.z - bf16_tof(h2)), l3 = bf16_rne(a.w - bf16_tof(h3));
    unsigned short l4 = bf16_rne(b.x - bf16_tof(h4)), l5 = bf16_rne(b.y - bf16_tof(h5)),
                   l6 = bf16_rne(b.z - bf16_tof(h6)), l7 = bf16_rne(b.w - bf16_tof(h7));
    hi.x = (unsigned)h0 | ((unsigned)h1 << 16); hi.y = (unsigned)h2 | ((unsigned)h3 << 16);
    hi.z = (unsigned)h4 | ((unsigned)h5 << 16); hi.w = (unsigned)h6 | ((unsigned)h7 << 16);
    lo.x = (unsigned)l0 | ((unsigned)l1 << 16); lo.y = (unsigned)l2 | ((unsigned)l3 << 16);
    lo.z = (unsigned)l4 | ((unsigned)l5 << 16); lo.w = (unsigned)l6 | ((unsigned)l7 << 16);
}

// Dynamic-LDS layout (bytes):
//   SB    @     0  (32768)  one quarter-pass of FR (2048 x 16B granules)
//   cnt   @ 32768  (  256)
//   lstk  @ 33024  ( 2048)  [64][8] candidate k
//   lsts  @ 35072  ( 2048)  [64][8] candidate score
//   win   @ 37120  (  256)
#define SMEM_BYTES 37376

__launch_bounds__(256, 4)
__global__ void vq_main(const float* __restrict__ x, const float* __restrict__ cb,
                        const float* __restrict__ cs,
                        const unsigned short* __restrict__ FR,
                        float* __restrict__ out) {
    extern __shared__ char smem[];
    uint4* SB   = (uint4*)(smem);
    int*   cnt  = (int*)  (smem + 32768);
    int*   lstk = (int*)  (smem + 33024);
    float* lsts = (float*)(smem + 35072);
    int*   win  = (int*)  (smem + 37120);

    const int t    = threadIdx.x;
    const int ln   = t & 63;
    const int wv   = t >> 6;
    const int m    = ln & 15;
    const int quad = ln >> 4;
    const int rowBlk0 = blockIdx.x * MBLK;

    // Issue stage for quarter-pass 0 immediately (overlaps x load + pack).
    {
        const char* gsrc = (const char*)FR;
#pragma unroll
        for (int i = 0; i < 8; ++i)
            g2lds16(gsrc + (size_t)(i * 256 + wv * 64 + ln) * 16,
                    (char*)SB + (size_t)(i * 256 + wv * 64) * 16);
    }

    if (t < 64) cnt[t] = 0;

    // A fragments: rows wv*16+m, dims quad*8.. (chunk0) / 32+quad*8.. (chunk1)
    const float* xrow = x + (size_t)(rowBlk0 + wv * 16 + m) * DDIM + quad * 8;
    U4S8 axh0, axh1, axl0, axl1;
    {
        float4 a0 = *(const float4*)(xrow);
        float4 b0 = *(const float4*)(xrow + 4);
        float4 a1 = *(const float4*)(xrow + 32);
        float4 b1 = *(const float4*)(xrow + 36);
        pack8(a0, b0, axh0.u, axl0.u);
        pack8(a1, b1, axh1.u, axl1.u);
    }

    float rm[4] = {INFINITY, INFINITY, INFINITY, INFINITY};

    for (int p = 0; p < 4; ++p) {
        __syncthreads();                       // stage p complete (drains vmcnt)

        float csr[8];
#pragma unroll
        for (int tt = 0; tt < 8; ++tt) csr[tt] = cs[p * 128 + tt * 16 + m];

        float s[4][8];
#pragma unroll
        for (int tt = 0; tt < 8; ++tt) {
            U4S8 bh0, bh1, bl0, bl1;
            bh0.u = SB[(tt * 4 + 0) * 64 + ln];
            bh1.u = SB[(tt * 4 + 1) * 64 + ln];
            bl0.u = SB[(tt * 4 + 2) * 64 + ln];
            bl1.u = SB[(tt * 4 + 3) * 64 + ln];
            f32x4 acc = {0.f, 0.f, 0.f, 0.f};
            acc = __builtin_amdgcn_mfma_f32_16x16x32_bf16(axh0.s, bh0.s, acc, 0, 0, 0);
            acc = __builtin_amdgcn_mfma_f32_16x16x32_bf16(axh1.s, bh1.s, acc, 0, 0, 0);
            acc = __builtin_amdgcn_mfma_f32_16x16x32_bf16(axl0.s, bh0.s, acc, 0, 0, 0);
            acc = __builtin_amdgcn_mfma_f32_16x16x32_bf16(axl1.s, bh1.s, acc, 0, 0, 0);
            acc = __builtin_amdgcn_mfma_f32_16x16x32_bf16(axh0.s, bl0.s, acc, 0, 0, 0);
            acc = __builtin_amdgcn_mfma_f32_16x16x32_bf16(axh1.s, bl1.s, acc, 0, 0, 0);
#pragma unroll
            for (int r = 0; r < 4; ++r)
                s[r][tt] = __fmaf_rn(-2.0f, acc[r], csr[tt]);
        }

        __syncthreads();                       // all waves done reading SB

        if (p < 3) {                           // prefetch next quarter-pass
            const char* gsrc = (const char*)FR + (size_t)(p + 1) * 32768;
#pragma unroll
            for (int i = 0; i < 8; ++i)
                g2lds16(gsrc + (size_t)(i * 256 + wv * 64 + ln) * 16,
                        (char*)SB + (size_t)(i * 256 + wv * 64) * 16);
        }

        // Row-min: in-lane tree + 4-step butterfly over the 16-lane group.
        // Row wv*16+quad*4+r is owned entirely by this group -> no LDS/barrier.
#pragma unroll
        for (int r = 0; r < 4; ++r) {
            float mn = s[r][0];
#pragma unroll
            for (int tt = 1; tt < 8; ++tt) mn = fminf(mn, s[r][tt]);
            mn = fminf(mn, __shfl_xor(mn, 1, 64));
            mn = fminf(mn, __shfl_xor(mn, 2, 64));
            mn = fminf(mn, __shfl_xor(mn, 4, 64));
            mn = fminf(mn, __shfl_xor(mn, 8, 64));
            rm[r] = fminf(rm[r], mn);
        }
        // Collect candidates within running-min + MARGIN (superset of
        // final-min + MARGIN since rm only decreases).
#pragma unroll
        for (int r = 0; r < 4; ++r) {
            float thr = rm[r] + MARGIN;
            int lrow = wv * 16 + quad * 4 + r;
#pragma unroll
            for (int tt = 0; tt < 8; ++tt) {
                if (s[r][tt] <= thr) {
                    int pos = atomicAdd(&cnt[lrow], 1);
                    if (pos < 8) {
                        lstk[lrow * 8 + pos] = p * 128 + tt * 16 + m;
                        lsts[lrow * 8 + pos] = s[r][tt];
                    }
                }
            }
        }
    }

    __syncthreads();   // safety: lists fully visible before final selection

    // Final selection: lane m<4 of each group owns row wv*16+quad*4+m.
    if (m < 4) {
        int lrow = wv * 16 + quad * 4 + m;
        float rmf = (m == 0) ? rm[0] : (m == 1) ? rm[1] : (m == 2) ? rm[2] : rm[3];
        float thr = rmf + MARGIN;
        int c = cnt[lrow];
        int kb;
        const float4* xr = (const float4*)(x + (size_t)(rowBlk0 + lrow) * DDIM);
        if (c <= 8) {
            int nc = 0, cand[8];
            for (int i = 0; i < c; ++i)
                if (lsts[lrow * 8 + i] <= thr) cand[nc++] = lstk[lrow * 8 + i];
            if (nc == 1) {
                kb = cand[0];
            } else {
                float xs = np_xs_stream(xr);
                float db = INFINITY; kb = 0x7fffffff;
                for (int j = 0; j < nc; ++j) {
                    int k = cand[j];
                    float a = dot_seq(xr, cb + (size_t)k * DDIM);
                    float d = __fadd_rn(__fadd_rn(xs, cs[k]), __fmul_rn(-2.0f, a));
                    if (d < db || (d == db && k < kb)) { db = d; kb = k; }
                }
            }
        } else {
            // Overflowed capacity: exact scan of all 512 (ascending + strict
            // '<' = numpy first occurrence).
            float xs = np_xs_stream(xr);
            float db = INFINITY; kb = 0;
            for (int k = 0; k < KCODES; ++k) {
                float a = dot_seq(xr, cb + (size_t)k * DDIM);
                float d = __fadd_rn(__fadd_rn(xs, cs[k]), __fmul_rn(-2.0f, a));
                if (d < db) { db = d; kb = k; }
            }
        }
        win[lrow] = kb;
        out[2 * ND + (size_t)(rowBlk0 + lrow)] = (float)kb;
    }
    __syncthreads();

    // Epilogue: z_q = z_q_bar = codebook[win], fully coalesced block writes.
#pragma unroll
    for (int i = 0; i < 4; ++i) {
        int g   = t + i * 256;                // 0..1023 float4-granules
        int row = g >> 4, cc = g & 15;
        int kb  = win[row];
        float4 v = *(const float4*)(cb + (size_t)kb * DDIM + cc * 4);
        size_t gr = (size_t)(rowBlk0 + row) * DDIM + (size_t)cc * 4;
        *(float4*)(out + gr) = v;
        *(float4*)(out + ND + gr) = v;
    }
}

extern "C" void kernel_launch(void* const* d_in, const int* in_sizes, int n_in,
                              void* d_out, int out_size, void* d_ws, size_t ws_size,
                              hipStream_t stream) {
    const float* z  = (const float*)d_in[0];   // [N, D] fp32
    const float* cb = (const float*)d_in[1];   // [K, D] fp32
    float* out = (float*)d_out;                // [N*D | N*D | N] fp32
    float* cs          = (float*)d_ws;                          // 512 f32
    unsigned short* FR = (unsigned short*)((char*)d_ws + 2048); // 128 KB frag-ordered

    (void)hipFuncSetAttribute((const void*)vq_main,
                              hipFuncAttributeMaxDynamicSharedMemorySize,
                              SMEM_BYTES);
    vq_prep<<<2, 256, 0, stream>>>(cb, cs, FR);
    vq_main<<<NROWS / MBLK, 256, SMEM_BYTES, stream>>>(z, cb, cs, FR, out);
}